// Round 1
// baseline (7705.276 us; speedup 1.0000x reference)
//
#include <hip/hip_runtime.h>

// TrajLSTM: 2-layer LSTM (H=1024) over T=64 steps + 16 autoregressive steps.
// B=1024, I=64. fp16 MFMA GEMMs with fused LSTM-cell epilogue; fp32 out-proj.
//
// Per step:
//   K1: gates1 = [x_t | h1] @ W1cat^T + b1  -> cell -> h1' (fp16)
//   K2: gates2 = [h1' | h2] @ W2cat^T + b2  -> cell -> h2' (fp16 + fp32)
//   K3: out_t  = h2' @ W_lin^T + b_lin (fp32), also fp16 copy for feedback
//
// h-state ping-pongs between S0/S1 (each 1024 x 2048 fp16 = [h1 | h2]) so a
// step never reads and writes the same buffer (cross-block hazard).

#define B_   1024
#define T_   64
#define I_   64
#define H_   1024
#define FUT_ 16
#define NST_ (T_ + FUT_)

typedef _Float16 half8_t __attribute__((ext_vector_type(8)));
typedef float    float4_t __attribute__((ext_vector_type(4)));

__device__ __forceinline__ float sigmoid_f(float x) {
    x = fminf(fmaxf(x, -30.f), 30.f);
    return __fdividef(1.f, 1.f + __expf(-x));
}
__device__ __forceinline__ float tanh_f(float x) {
    x = fminf(fmaxf(x, -15.f), 15.f);
    float e = __expf(2.f * x);
    return 1.f - 2.f * __fdividef(1.f, e + 1.f);
}

// ---------------- one-time per-call conversion / packing -------------------
// W1c: (4096 x 1088) fp16 rows = [W_ih1 | W_hh1]
// W2c: (4096 x 2048) fp16 rows = [W_ih2 | W_hh2]
// xh:  (B,T,I) fp16 copy of x;  b1/b2 = b_ih + b_hh (fp32)
__global__ void convert_all(const float* __restrict__ x,
    const float* __restrict__ Wih1, const float* __restrict__ Whh1,
    const float* __restrict__ bih1, const float* __restrict__ bhh1,
    const float* __restrict__ Wih2, const float* __restrict__ Whh2,
    const float* __restrict__ bih2, const float* __restrict__ bhh2,
    _Float16* __restrict__ W1c, _Float16* __restrict__ W2c,
    _Float16* __restrict__ xh, float* __restrict__ b1, float* __restrict__ b2)
{
    size_t idx = (size_t)blockIdx.x * 256 + threadIdx.x;
    const size_t n1 = (size_t)4096 * 1088;
    const size_t n2 = (size_t)4096 * 2048;
    const size_t nx = (size_t)B_ * T_ * I_;
    if (idx < n1) {
        size_t n = idx / 1088, k = idx % 1088;
        float v = (k < 64) ? Wih1[n * 64 + k] : Whh1[n * 1024 + (k - 64)];
        W1c[idx] = (_Float16)v;
    } else if ((idx -= n1) < n2) {
        size_t n = idx >> 11, k = idx & 2047;
        float v = (k < 1024) ? Wih2[(n << 10) + k] : Whh2[(n << 10) + (k - 1024)];
        W2c[idx] = (_Float16)v;
    } else if ((idx -= n2) < nx) {
        xh[idx] = (_Float16)x[idx];
    } else if ((idx -= nx) < 4096) {
        b1[idx] = bih1[idx] + bhh1[idx];
    } else if ((idx -= 4096) < 4096) {
        b2[idx] = bih2[idx] + bhh2[idx];
    }
}

// ---------------- GEMM + fused LSTM cell -----------------------------------
// Block: 64 batch rows x 64 H-cols, all 4 gates (effective 64x256 GEMM tile).
// A = [Aa (Ka cols) | Ab (Kb cols)], both K-contiguous fp16, Ka % 64 == 0.
// W rows: [i(0:1024) | f | g | o] x (Ka+Kb) cols.
// 4 waves; wave w covers H-cols [w*16, w*16+16) for all 4 gates, all 64 rows.
// Epilogue: lane holds i,f,g,o of the same (b,j) -> register-resident cell.
__global__ __launch_bounds__(256) void lstm_gemm(
    const _Float16* __restrict__ Aa, int lda, int Ka,
    const _Float16* __restrict__ Ab, int ldb, int Kb,
    const _Float16* __restrict__ W, int ldw,
    const float* __restrict__ bias,
    float* __restrict__ cvec,            // fp32 c state (B x 1024), in/out
    _Float16* __restrict__ hdst,         // fp16 h out, row stride 2048
    float* __restrict__ h32dst)          // optional fp32 h out (B x 1024)
{
    __shared__ _Float16 sA[64][72];      // +8 pad: bank-conflict-free frags
    __shared__ _Float16 sB[256][72];     // 4 gate regions x 64 rows

    const int tid = threadIdx.x;
    const int h0 = blockIdx.x * 64;      // H tile
    const int m0 = blockIdx.y * 64;      // batch tile
    const int lane = tid & 63, w = tid >> 6;
    const int lr = lane & 15, lq = lane >> 4;
    const int Kt = Ka + Kb;

    float4_t acc[4][4];                  // [gate][rowtile]
    #pragma unroll
    for (int g = 0; g < 4; ++g)
        #pragma unroll
        for (int rt = 0; rt < 4; ++rt)
            #pragma unroll
            for (int e = 0; e < 4; ++e) acc[g][rt][e] = 0.f;

    for (int k0 = 0; k0 < Kt; k0 += 64) {
        // stage A tile: 64 rows x 64 k (512 16B segs, 2/thread)
        #pragma unroll
        for (int s2 = 0; s2 < 2; ++s2) {
            int seg = tid + s2 * 256;
            int row = seg >> 3, c8 = seg & 7;
            int gk = k0 + c8 * 8;
            const _Float16* src; int ld, kb;
            if (gk < Ka) { src = Aa; ld = lda; kb = gk; }
            else         { src = Ab; ld = ldb; kb = gk - Ka; }
            *(half8_t*)&sA[row][c8 * 8] =
                *(const half8_t*)&src[(size_t)(m0 + row) * ld + kb];
        }
        // stage B tile: 4 gates x 64 W-rows x 64 k (2048 segs, 8/thread)
        #pragma unroll
        for (int s2 = 0; s2 < 8; ++s2) {
            int seg = tid + s2 * 256;
            int row = seg >> 3, c8 = seg & 7;
            int wr = ((row >> 6) << 10) + h0 + (row & 63);
            *(half8_t*)&sB[row][c8 * 8] =
                *(const half8_t*)&W[(size_t)wr * ldw + k0 + c8 * 8];
        }
        __syncthreads();
        #pragma unroll
        for (int ks = 0; ks < 2; ++ks) {
            const int koff = ks * 32 + lq * 8;
            half8_t af[4], bf[4];
            #pragma unroll
            for (int rt = 0; rt < 4; ++rt)
                af[rt] = *(const half8_t*)&sA[rt * 16 + lr][koff];
            #pragma unroll
            for (int g = 0; g < 4; ++g)
                bf[g] = *(const half8_t*)&sB[g * 64 + w * 16 + lr][koff];
            #pragma unroll
            for (int g = 0; g < 4; ++g)
                #pragma unroll
                for (int rt = 0; rt < 4; ++rt)
                    acc[g][rt] = __builtin_amdgcn_mfma_f32_16x16x32_f16(
                        af[rt], bf[g], acc[g][rt], 0, 0, 0);
        }
        __syncthreads();
    }

    // fused LSTM cell epilogue (i,f,g,o of same (b,j) live in same lane/reg)
    const int j = h0 + w * 16 + lr;
    const float bi = bias[j], bf2 = bias[1024 + j];
    const float bg = bias[2048 + j], bo = bias[3072 + j];
    #pragma unroll
    for (int rt = 0; rt < 4; ++rt) {
        #pragma unroll
        for (int e = 0; e < 4; ++e) {
            const int brow = m0 + rt * 16 + lq * 4 + e;
            float gi = sigmoid_f(acc[0][rt][e] + bi);
            float gf = sigmoid_f(acc[1][rt][e] + bf2);
            float gg = tanh_f(acc[2][rt][e] + bg);
            float go = sigmoid_f(acc[3][rt][e] + bo);
            const size_t ci = (size_t)brow * 1024 + j;
            float cn = gf * cvec[ci] + gi * gg;
            cvec[ci] = cn;
            float h = go * tanh_f(cn);
            hdst[(size_t)brow * 2048 + j] = (_Float16)h;
            if (h32dst) h32dst[ci] = h;
        }
    }
}

// ---------------- out projection (fp32) ------------------------------------
// out[b,i] = h2[b,:] . W_lin[i,:] + b_lin[i];  block: 4 b-rows x 64 i-cols.
__global__ __launch_bounds__(256) void out_proj(
    const float* __restrict__ h2f, const float* __restrict__ Wlin,
    const float* __restrict__ blin, float* __restrict__ outp,
    _Float16* __restrict__ xout)
{
    __shared__ float sW[64][132];   // +4 pad
    __shared__ float sH[4][128];
    const int tid = threadIdx.x;
    const int i = tid & 63, bl = tid >> 6;
    const int b0 = blockIdx.x * 4;
    float s = 0.f;
    for (int kc = 0; kc < 1024; kc += 128) {
        #pragma unroll
        for (int t2 = 0; t2 < 8; ++t2) {   // 64x128 W chunk, coalesced
            int seg = tid + t2 * 256;
            int r = seg >> 5, c4 = seg & 31;
            *(float4*)&sW[r][c4 * 4] =
                *(const float4*)&Wlin[(size_t)r * 1024 + kc + c4 * 4];
        }
        if (tid < 128) {
            int r = tid >> 5, c4 = tid & 31;
            *(float4*)&sH[r][c4 * 4] =
                *(const float4*)&h2f[(size_t)(b0 + r) * 1024 + kc + c4 * 4];
        }
        __syncthreads();
        #pragma unroll 8
        for (int k4 = 0; k4 < 32; ++k4) {
            float4 wv = *(float4*)&sW[i][k4 * 4];
            float4 av = *(float4*)&sH[bl][k4 * 4];
            s += av.x * wv.x + av.y * wv.y + av.z * wv.z + av.w * wv.w;
        }
        __syncthreads();
    }
    s += blin[i];
    const int b = b0 + bl;
    outp[(size_t)b * (NST_ * I_) + i] = s;       // outp pre-offset by t*64
    xout[b * 64 + i] = (_Float16)s;              // fp16 feedback for t >= 64
}

// ---------------------------------------------------------------------------
extern "C" void kernel_launch(void* const* d_in, const int* in_sizes, int n_in,
                              void* d_out, int out_size, void* d_ws, size_t ws_size,
                              hipStream_t stream) {
    (void)in_sizes; (void)n_in; (void)out_size; (void)ws_size;
    const float* x    = (const float*)d_in[0];
    const float* Wih1 = (const float*)d_in[1];
    const float* Whh1 = (const float*)d_in[2];
    const float* bih1 = (const float*)d_in[3];
    const float* bhh1 = (const float*)d_in[4];
    const float* Wih2 = (const float*)d_in[5];
    const float* Whh2 = (const float*)d_in[6];
    const float* bih2 = (const float*)d_in[7];
    const float* bhh2 = (const float*)d_in[8];
    const float* Wlin = (const float*)d_in[9];
    const float* blin = (const float*)d_in[10];

    char* p = (char*)d_ws;
    auto alloc = [&](size_t bytes) {
        char* r = p; p += (bytes + 255) & ~(size_t)255; return r;
    };
    _Float16* W1c = (_Float16*)alloc((size_t)4096 * 1088 * 2);
    _Float16* W2c = (_Float16*)alloc((size_t)4096 * 2048 * 2);
    _Float16* xh  = (_Float16*)alloc((size_t)B_ * T_ * I_ * 2);
    _Float16* S0  = (_Float16*)alloc((size_t)B_ * 2048 * 2);
    _Float16* S1  = (_Float16*)alloc((size_t)B_ * 2048 * 2);
    float* c1  = (float*)alloc((size_t)B_ * H_ * 4);
    float* c2  = (float*)alloc((size_t)B_ * H_ * 4);
    float* h2f = (float*)alloc((size_t)B_ * H_ * 4);
    _Float16* xout = (_Float16*)alloc((size_t)B_ * I_ * 2);
    float* b1 = (float*)alloc(4096 * 4);
    float* b2 = (float*)alloc(4096 * 4);

    // zero initial state (ws is poisoned 0xAA before every call)
    hipMemsetAsync(S0, 0, (size_t)B_ * 2048 * 2, stream);
    hipMemsetAsync(c1, 0, (size_t)B_ * H_ * 4, stream);
    hipMemsetAsync(c2, 0, (size_t)B_ * H_ * 4, stream);

    {
        const size_t total = (size_t)4096 * 1088 + (size_t)4096 * 2048 +
                             (size_t)B_ * T_ * I_ + 8192;
        const int grid = (int)((total + 255) / 256);
        convert_all<<<grid, 256, 0, stream>>>(x, Wih1, Whh1, bih1, bhh1,
            Wih2, Whh2, bih2, bhh2, W1c, W2c, xh, b1, b2);
    }

    for (int t = 0; t < NST_; ++t) {
        _Float16* Sp = (t & 1) ? S1 : S0;   // read state
        _Float16* Sq = (t & 1) ? S0 : S1;   // write state
        const _Float16* Ax; int ldax;
        if (t < T_) { Ax = xh + (size_t)t * I_; ldax = T_ * I_; }
        else        { Ax = xout;               ldax = I_; }
        // layer 1: gates1 = [x_t | h1] @ W1c^T
        lstm_gemm<<<dim3(16, 16), 256, 0, stream>>>(
            Ax, ldax, 64, Sp, 2048, 1024, W1c, 1088, b1, c1,
            Sq, nullptr);
        // layer 2: gates2 = [h1' | h2] @ W2c^T
        lstm_gemm<<<dim3(16, 16), 256, 0, stream>>>(
            Sq, 2048, 1024, Sp + 1024, 2048, 1024, W2c, 2048, b2, c2,
            Sq + 1024, h2f);
        // out projection (fp32) + fp16 feedback copy
        out_proj<<<256, 256, 0, stream>>>(
            h2f, Wlin, blin, (float*)d_out + (size_t)t * I_, xout);
    }
}

// Round 2
// 6244.946 us; speedup vs baseline: 1.2338x; 1.2338x over previous
//
#include <hip/hip_runtime.h>

// TrajLSTM: 2-layer LSTM (H=1024) over T=64 steps + 16 autoregressive steps.
// B=1024, I=64. fp16 MFMA GEMMs, fused LSTM-cell epilogue, fp32 out-proj.
//
// State buffer row (fp16, stride 2176): [x(64) | pad(64) | h1(1024) | h2(1024)]
// Ping-pong S0/S1. Layer1 reads cols [0:1152) of Sp; layer2 reads h1 from Sq
// and h2 from Sp (the split-K halves align exactly with that boundary).
//
// Weights pre-packed fragment-major: chunk(hgrp, j, g) = 1KB holding the MFMA
// B-fragment for 16 gate-rows x 32 k: lane l -> W[g*1024+hgrp*16+(l&15)]
// [j*32+(l>>4)*8 .. +8]. bf load = one coalesced dwordx4 at base + lane*16.
// B has zero cross-wave reuse -> no LDS staging for B at all.
//
// lstm_gemm block: 256 thr = 4 waves = 2 H-groups x 2 K-halves (split-K),
// grid (32,16) = 512 blocks -> 2 blocks/CU, 8 waves/CU.

#define B_   1024
#define T_   64
#define I_   64
#define H_   1024
#define FUT_ 16
#define NST_ (T_ + FUT_)
#define SROW 2176

typedef _Float16 half8_t  __attribute__((ext_vector_type(8)));
typedef float    float4_t __attribute__((ext_vector_type(4)));

__device__ __forceinline__ float sigmoid_f(float x) {
    x = fminf(fmaxf(x, -30.f), 30.f);
    return __fdividef(1.f, 1.f + __expf(-x));
}
__device__ __forceinline__ float tanh_f(float x) {
    x = fminf(fmaxf(x, -15.f), 15.f);
    float e = __expf(2.f * x);
    return 1.f - 2.f * __fdividef(1.f, e + 1.f);
}

// ---------------- one-time conversion / packing ----------------------------
// W1p: 64 hgrp x 36 j x 4 g x 1KB chunks (logical 4096 x 1152, cols 64..128=0)
// W2p: 64 hgrp x 64 j x 4 g x 1KB chunks (logical 4096 x 2048)
// S0 x-slot <- x[:,0,:]; b1/b2 = b_ih + b_hh
__global__ void convert_all(const float* __restrict__ x,
    const float* __restrict__ Wih1, const float* __restrict__ Whh1,
    const float* __restrict__ bih1, const float* __restrict__ bhh1,
    const float* __restrict__ Wih2, const float* __restrict__ Whh2,
    const float* __restrict__ bih2, const float* __restrict__ bhh2,
    _Float16* __restrict__ W1p, _Float16* __restrict__ W2p,
    _Float16* __restrict__ S0, float* __restrict__ b1, float* __restrict__ b2)
{
    size_t idx = (size_t)blockIdx.x * 256 + threadIdx.x;
    const size_t nc1 = 589824;    // 4096*1152/8 chunks-of-8
    const size_t nc2 = 1048576;   // 4096*2048/8
    const size_t nx  = 65536;     // B_ * I_
    if (idx < nc1) {
        int c = (int)idx;
        int lane = c & 63, g = (c >> 6) & 3, rem = c >> 8;
        int j = rem % 36, hgrp = rem / 36;
        int row = (g << 10) + hgrp * 16 + (lane & 15);
        int kb = j * 32 + (lane >> 4) * 8;
        _Float16* o = &W1p[(size_t)c * 8];
        if (kb < 64) {
            #pragma unroll
            for (int i = 0; i < 8; ++i) o[i] = (_Float16)Wih1[row * 64 + kb + i];
        } else if (kb < 128) {
            #pragma unroll
            for (int i = 0; i < 8; ++i) o[i] = (_Float16)0.f;
        } else {
            #pragma unroll
            for (int i = 0; i < 8; ++i) o[i] = (_Float16)Whh1[(size_t)row * 1024 + kb - 128 + i];
        }
    } else if ((idx -= nc1) < nc2) {
        int c = (int)idx;
        int lane = c & 63, g = (c >> 6) & 3, rem = c >> 8;
        int j = rem & 63, hgrp = rem >> 6;
        int row = (g << 10) + hgrp * 16 + (lane & 15);
        int kb = j * 32 + (lane >> 4) * 8;
        _Float16* o = &W2p[(size_t)c * 8];
        if (kb < 1024) {
            #pragma unroll
            for (int i = 0; i < 8; ++i) o[i] = (_Float16)Wih2[(size_t)row * 1024 + kb + i];
        } else {
            #pragma unroll
            for (int i = 0; i < 8; ++i) o[i] = (_Float16)Whh2[(size_t)row * 1024 + kb - 1024 + i];
        }
    } else if ((idx -= nc2) < nx) {
        int b = (int)(idx >> 6), i = (int)(idx & 63);
        S0[(size_t)b * SROW + i] = (_Float16)x[(size_t)b * (T_ * I_) + i];
    } else if ((idx -= nx) < 4096) {
        b1[idx] = bih1[idx] + bhh1[idx];
    } else if ((idx -= 4096) < 4096) {
        b2[idx] = bih2[idx] + bhh2[idx];
    }
}

// ---------------- GEMM + fused LSTM cell -----------------------------------
// Output tile per block: 64 batch x 32 H-cols x 4 gates. Wave w: hw=w&1
// (H-group), kh=w>>1 (K-half). A k-range: half0 from Alo, half1 from Ahi
// (pre-offset so local k' = k - Ksh*32). Ksh = K32-steps per half.
__global__ __launch_bounds__(256, 2) void lstm_gemm(
    const _Float16* __restrict__ Alo, const _Float16* __restrict__ Ahi,
    const _Float16* __restrict__ Wp,
    const int iters,                   // Kt/128
    const int Ksh,                     // = iters*2
    const float* __restrict__ bias,
    float* __restrict__ cvec,          // fp32 c state (B x 1024)
    _Float16* __restrict__ hdst,       // h out, row stride SROW
    float* __restrict__ h32dst)        // optional fp32 h out (B x 1024)
{
    __shared__ __align__(16) _Float16 sA[64][136];   // 128 data + 8 pad

    const int tid = threadIdx.x;
    const int lane = tid & 63, w = tid >> 6;
    const int hw = w & 1, kh = w >> 1;
    const int lr = lane & 15, lq = lane >> 4;
    const int h0 = blockIdx.x * 32;
    const int m0 = blockIdx.y * 64;
    const int hgrp = blockIdx.x * 2 + hw;

    // per-wave packed-W cursor: 4KB per K32 step, this wave starts at its half
    const char* wptr = (const char*)Wp
        + ((size_t)hgrp * (2 * Ksh) + (size_t)kh * Ksh) * 4096
        + (size_t)lane * 16;

    // per-thread A staging address (grp fixed per thread)
    const int srow0 = tid >> 4;              // + s*16
    const int grp = tid & 15;
    const _Float16* abase = (grp < 8 ? Alo : Ahi) + (size_t)(grp & 7) * 8;
    const _Float16* arow = abase + (size_t)(m0 + srow0) * SROW;

    float4_t acc[4][4];
    #pragma unroll
    for (int g = 0; g < 4; ++g)
        #pragma unroll
        for (int rt = 0; rt < 4; ++rt)
            #pragma unroll
            for (int e = 0; e < 4; ++e) acc[g][rt][e] = 0.f;

    for (int i = 0; i < iters; ++i) {
        // stage A: 64 rows x 128 halves (64 per K-half), 4 x 16B per thread
        #pragma unroll
        for (int s = 0; s < 4; ++s)
            *(half8_t*)&sA[srow0 + s * 16][grp * 8] =
                *(const half8_t*)(arow + (size_t)s * 16 * SROW + i * 64);
        __syncthreads();
        #pragma unroll
        for (int ks = 0; ks < 2; ++ks) {
            half8_t af[4], bf[4];
            #pragma unroll
            for (int g = 0; g < 4; ++g)
                bf[g] = *(const half8_t*)(wptr + (ks * 4 + g) * 1024);
            #pragma unroll
            for (int rt = 0; rt < 4; ++rt)
                af[rt] = *(const half8_t*)&sA[rt * 16 + lr][kh * 64 + ks * 32 + lq * 8];
            #pragma unroll
            for (int g = 0; g < 4; ++g)
                #pragma unroll
                for (int rt = 0; rt < 4; ++rt)
                    acc[g][rt] = __builtin_amdgcn_mfma_f32_16x16x32_f16(
                        af[rt], bf[g], acc[g][rt], 0, 0, 0);
        }
        wptr += 8192;
        __syncthreads();
    }

    // split-K combine through LDS (2 rounds x 2 gates, 16 KB <= sA)
    float* scr = (float*)&sA[0][0];
    #pragma unroll
    for (int gp = 0; gp < 2; ++gp) {
        if (kh == 1) {
            #pragma unroll
            for (int g2 = 0; g2 < 2; ++g2)
                #pragma unroll
                for (int rt = 0; rt < 4; ++rt) {
                    int slot = ((hw * 2 + g2) * 4 + rt) * 64 + lane;
                    *(float4_t*)&scr[slot * 4] = acc[gp * 2 + g2][rt];
                }
        }
        __syncthreads();
        if (kh == 0) {
            #pragma unroll
            for (int g2 = 0; g2 < 2; ++g2)
                #pragma unroll
                for (int rt = 0; rt < 4; ++rt) {
                    int slot = ((hw * 2 + g2) * 4 + rt) * 64 + lane;
                    acc[gp * 2 + g2][rt] += *(const float4_t*)&scr[slot * 4];
                }
        }
        __syncthreads();
    }
    if (kh != 0) return;

    // fused LSTM cell epilogue (kh==0 waves): lane holds i,f,g,o of same (b,j)
    const int j = h0 + hw * 16 + lr;
    const float bi = bias[j], bff = bias[1024 + j];
    const float bg = bias[2048 + j], bo = bias[3072 + j];
    #pragma unroll
    for (int rt = 0; rt < 4; ++rt) {
        #pragma unroll
        for (int e = 0; e < 4; ++e) {
            const int brow = m0 + rt * 16 + lq * 4 + e;
            float gi = sigmoid_f(acc[0][rt][e] + bi);
            float gf = sigmoid_f(acc[1][rt][e] + bff);
            float gg = tanh_f(acc[2][rt][e] + bg);
            float go = sigmoid_f(acc[3][rt][e] + bo);
            const size_t ci = (size_t)brow * 1024 + j;
            float cn = gf * cvec[ci] + gi * gg;
            cvec[ci] = cn;
            float h = go * tanh_f(cn);
            hdst[(size_t)brow * SROW + j] = (_Float16)h;
            if (h32dst) h32dst[ci] = h;
        }
    }
}

// ---------------- out projection (fp32) + feedback -------------------------
// out[b,i] = h2[b,:] . W_lin[i,:] + b_lin[i]. Also writes x(t+1) into the
// next state buffer's x-slot: from xsrc (t+1 < T) or the computed output.
__global__ __launch_bounds__(256) void out_proj(
    const float* __restrict__ h2f, const float* __restrict__ Wlin,
    const float* __restrict__ blin, float* __restrict__ outp,
    _Float16* __restrict__ xdst, const float* __restrict__ xsrc)
{
    __shared__ float sW[64][132];
    __shared__ float sH[4][128];
    const int tid = threadIdx.x;
    const int i = tid & 63, bl = tid >> 6;
    const int b0 = blockIdx.x * 4;
    float s = 0.f;
    for (int kc = 0; kc < 1024; kc += 128) {
        #pragma unroll
        for (int t2 = 0; t2 < 8; ++t2) {
            int seg = tid + t2 * 256;
            int r = seg >> 5, c4 = seg & 31;
            *(float4*)&sW[r][c4 * 4] =
                *(const float4*)&Wlin[(size_t)r * 1024 + kc + c4 * 4];
        }
        if (tid < 128) {
            int r = tid >> 5, c4 = tid & 31;
            *(float4*)&sH[r][c4 * 4] =
                *(const float4*)&h2f[(size_t)(b0 + r) * 1024 + kc + c4 * 4];
        }
        __syncthreads();
        #pragma unroll 8
        for (int k4 = 0; k4 < 32; ++k4) {
            float4 wv = *(float4*)&sW[i][k4 * 4];
            float4 av = *(float4*)&sH[bl][k4 * 4];
            s += av.x * wv.x + av.y * wv.y + av.z * wv.z + av.w * wv.w;
        }
        __syncthreads();
    }
    s += blin[i];
    const int b = b0 + bl;
    outp[(size_t)b * (NST_ * I_) + i] = s;
    float xv = xsrc ? xsrc[(size_t)b * (T_ * I_) + i] : s;
    xdst[(size_t)b * SROW + i] = (_Float16)xv;
}

// ---------------------------------------------------------------------------
extern "C" void kernel_launch(void* const* d_in, const int* in_sizes, int n_in,
                              void* d_out, int out_size, void* d_ws, size_t ws_size,
                              hipStream_t stream) {
    (void)in_sizes; (void)n_in; (void)out_size; (void)ws_size;
    const float* x    = (const float*)d_in[0];
    const float* Wih1 = (const float*)d_in[1];
    const float* Whh1 = (const float*)d_in[2];
    const float* bih1 = (const float*)d_in[3];
    const float* bhh1 = (const float*)d_in[4];
    const float* Wih2 = (const float*)d_in[5];
    const float* Whh2 = (const float*)d_in[6];
    const float* bih2 = (const float*)d_in[7];
    const float* bhh2 = (const float*)d_in[8];
    const float* Wlin = (const float*)d_in[9];
    const float* blin = (const float*)d_in[10];

    char* p = (char*)d_ws;
    auto alloc = [&](size_t bytes) {
        char* r = p; p += (bytes + 255) & ~(size_t)255; return r;
    };
    _Float16* W1p = (_Float16*)alloc((size_t)4096 * 1152 * 2);
    _Float16* W2p = (_Float16*)alloc((size_t)4096 * 2048 * 2);
    _Float16* S0  = (_Float16*)alloc((size_t)B_ * SROW * 2);
    _Float16* S1  = (_Float16*)alloc((size_t)B_ * SROW * 2);
    float* c1  = (float*)alloc((size_t)B_ * H_ * 4);
    float* c2  = (float*)alloc((size_t)B_ * H_ * 4);
    float* h2f = (float*)alloc((size_t)B_ * H_ * 4);
    float* b1  = (float*)alloc(4096 * 4);
    float* b2  = (float*)alloc(4096 * 4);

    hipMemsetAsync(S0, 0, (size_t)B_ * SROW * 2, stream);
    hipMemsetAsync(S1, 0, (size_t)B_ * SROW * 2, stream);
    hipMemsetAsync(c1, 0, (size_t)B_ * H_ * 4, stream);
    hipMemsetAsync(c2, 0, (size_t)B_ * H_ * 4, stream);

    {
        const size_t total = 589824 + 1048576 + 65536 + 8192;
        convert_all<<<(int)((total + 255) / 256), 256, 0, stream>>>(
            x, Wih1, Whh1, bih1, bhh1, Wih2, Whh2, bih2, bhh2,
            W1p, W2p, S0, b1, b2);
    }

    for (int t = 0; t < NST_; ++t) {
        _Float16* Sp = (t & 1) ? S1 : S0;
        _Float16* Sq = (t & 1) ? S0 : S1;
        // layer 1: A = Sp cols [0:1152) = [x|pad|h1]; halves of 576
        lstm_gemm<<<dim3(32, 16), 256, 0, stream>>>(
            Sp, Sp + 576, W1p, 9, 18, b1, c1, Sq + 128, nullptr);
        // layer 2: A = [h1'(Sq) | h2(Sp)]; halves of 1024 align with sources
        lstm_gemm<<<dim3(32, 16), 256, 0, stream>>>(
            Sq + 128, Sp + 1152, W2p, 16, 32, b2, c2, Sq + 1152, h2f);
        // projection + x-feedback into Sq's x-slot
        const float* xsrc = (t + 1 < T_) ? (x + (size_t)(t + 1) * I_) : nullptr;
        out_proj<<<256, 256, 0, stream>>>(
            h2f, Wlin, blin, (float*)d_out + (size_t)t * I_, Sq, xsrc);
    }
}

// Round 3
// 3770.501 us; speedup vs baseline: 2.0436x; 1.6563x over previous
//
#include <hip/hip_runtime.h>

// TrajLSTM: 2-layer LSTM (H=1024) over T=64 steps + 16 autoregressive steps.
// B=1024, I=64. fp16 MFMA GEMMs, fused LSTM-cell epilogue, fp16-MFMA out-proj.
//
// State rows (fp16, stride 2176): [h1(1024) | x(64) | pad(64) | h2(1024)],
// THREE buffers rotating by t%3 so one fused dispatch can contain
// {L2(t), L1(t+1), proj(t-1), xcopy(t+2)} with no intra-dispatch hazards:
//   L1(t+1): reads S[(t+1)%3][0:1152), writes h1 -> S[(t+2)%3][0:1024)
//   L2(t):   reads S[(t+1)%3][0:1024) + S[t%3][1152:), writes S[(t+1)%3]+1152
//   proj(t-1): reads S[t%3]+1152, writes d_out
//   xcopy:   writes x(t+2) -> S[(t+2)%3]+1024
// Future phase (t>=64) is truly serial (x feedback): 3 dispatches/step, with
// proj writing both d_out and the next x-slot.
//
// Weights pre-packed MFMA-fragment-major (1KB chunks, load = base+lane*16).

#define B_   1024
#define T_   64
#define I_   64
#define H_   1024
#define FUT_ 16
#define NST_ (T_ + FUT_)
#define SROW 2176

typedef _Float16 half8_t  __attribute__((ext_vector_type(8)));
typedef float    float4_t __attribute__((ext_vector_type(4)));

__device__ __forceinline__ float sigmoid_f(float x) {
    x = fminf(fmaxf(x, -30.f), 30.f);
    return __fdividef(1.f, 1.f + __expf(-x));
}
__device__ __forceinline__ float tanh_f(float x) {
    x = fminf(fmaxf(x, -15.f), 15.f);
    float e = __expf(2.f * x);
    return 1.f - 2.f * __fdividef(1.f, e + 1.f);
}

// ---------------- one-time conversion / packing ----------------------------
// W1p: [hgrp 64][kstep 36][gate 4][1KB]  (logical K=1152: h1|x|pad0)
// W2p: [hgrp 64][kstep 64][gate 4][1KB]  (logical K=2048: h1'|h2)
// Wlp: [hgrp 4 ][kstep 32][1KB]          (64 x 1024)
// x(0)->S0 x-slot, x(1)->S1 x-slot; b1/b2 = b_ih + b_hh
__global__ void convert_all(const float* __restrict__ x,
    const float* __restrict__ Wih1, const float* __restrict__ Whh1,
    const float* __restrict__ bih1, const float* __restrict__ bhh1,
    const float* __restrict__ Wih2, const float* __restrict__ Whh2,
    const float* __restrict__ bih2, const float* __restrict__ bhh2,
    const float* __restrict__ Wlin,
    _Float16* __restrict__ W1p, _Float16* __restrict__ W2p,
    _Float16* __restrict__ Wlp,
    _Float16* __restrict__ S0x, _Float16* __restrict__ S1x,
    float* __restrict__ b1, float* __restrict__ b2)
{
    size_t idx = (size_t)blockIdx.x * 256 + threadIdx.x;
    const size_t nc1 = 589824;    // 4096*1152/8
    const size_t nc2 = 1048576;   // 4096*2048/8
    const size_t nc3 = 8192;      // 64*1024/8
    const size_t nx  = 65536;     // B_*I_
    if (idx < nc1) {
        int c = (int)idx;
        int lane = c & 63, g = (c >> 6) & 3, rem = c >> 8;
        int j = rem % 36, hgrp = rem / 36;
        int row = (g << 10) + hgrp * 16 + (lane & 15);
        int kb = j * 32 + (lane >> 4) * 8;
        _Float16* o = &W1p[(size_t)c * 8];
        if (kb < 1024) {
            #pragma unroll
            for (int i = 0; i < 8; ++i) o[i] = (_Float16)Whh1[(size_t)row * 1024 + kb + i];
        } else if (kb < 1088) {
            #pragma unroll
            for (int i = 0; i < 8; ++i) o[i] = (_Float16)Wih1[row * 64 + (kb - 1024) + i];
        } else {
            #pragma unroll
            for (int i = 0; i < 8; ++i) o[i] = (_Float16)0.f;
        }
    } else if ((idx -= nc1) < nc2) {
        int c = (int)idx;
        int lane = c & 63, g = (c >> 6) & 3, rem = c >> 8;
        int j = rem & 63, hgrp = rem >> 6;
        int row = (g << 10) + hgrp * 16 + (lane & 15);
        int kb = j * 32 + (lane >> 4) * 8;
        _Float16* o = &W2p[(size_t)c * 8];
        if (kb < 1024) {
            #pragma unroll
            for (int i = 0; i < 8; ++i) o[i] = (_Float16)Wih2[(size_t)row * 1024 + kb + i];
        } else {
            #pragma unroll
            for (int i = 0; i < 8; ++i) o[i] = (_Float16)Whh2[(size_t)row * 1024 + kb - 1024 + i];
        }
    } else if ((idx -= nc2) < nc3) {
        int c = (int)idx;
        int lane = c & 63, j = (c >> 6) & 31, hgrp = c >> 11;
        int row = hgrp * 16 + (lane & 15);
        int kb = j * 32 + (lane >> 4) * 8;
        _Float16* o = &Wlp[(size_t)c * 8];
        #pragma unroll
        for (int i = 0; i < 8; ++i) o[i] = (_Float16)Wlin[(size_t)row * 1024 + kb + i];
    } else if ((idx -= nc3) < nx) {
        int b = (int)(idx >> 6), i = (int)(idx & 63);
        S0x[(size_t)b * SROW + i] = (_Float16)x[(size_t)b * (T_ * I_) + i];
    } else if ((idx -= nx) < nx) {
        int b = (int)(idx >> 6), i = (int)(idx & 63);
        S1x[(size_t)b * SROW + i] = (_Float16)x[(size_t)b * (T_ * I_) + 64 + i];
    } else if ((idx -= nx) < 4096) {
        b1[idx] = bih1[idx] + bhh1[idx];
    } else if ((idx -= 4096) < 4096) {
        b2[idx] = bih2[idx] + bhh2[idx];
    }
}

// ---------------- role bodies ----------------------------------------------
// GEMM+cell: block tile 64 batch x 32 H x 4 gates; 4 waves = 2 hw x 2 kh.
__device__ __forceinline__ void gemm_body(_Float16 (*sA)[136],
    const _Float16* __restrict__ Alo, const _Float16* __restrict__ Ahi,
    const _Float16* __restrict__ Wp, const int iters, const int Ksh,
    const float* __restrict__ bias, float* __restrict__ cvec,
    _Float16* __restrict__ hdst, const int unit)
{
    const int tid = threadIdx.x;
    const int lane = tid & 63, w = tid >> 6;
    const int hw = w & 1, kh = w >> 1;
    const int lr = lane & 15, lq = lane >> 4;
    const int ht = unit & 31, mt = unit >> 5;
    const int h0 = ht * 32, m0 = mt * 64;
    const int hgrp = ht * 2 + hw;

    const char* wptr = (const char*)Wp
        + ((size_t)hgrp * (2 * Ksh) + (size_t)kh * Ksh) * 4096
        + (size_t)lane * 16;

    const int srow0 = tid >> 4, grp = tid & 15;
    const _Float16* abase = (grp < 8 ? Alo : Ahi) + (size_t)(grp & 7) * 8;
    const _Float16* arow = abase + (size_t)(m0 + srow0) * SROW;

    float4_t acc[4][4];
    #pragma unroll
    for (int g = 0; g < 4; ++g)
        #pragma unroll
        for (int rt = 0; rt < 4; ++rt)
            #pragma unroll
            for (int e = 0; e < 4; ++e) acc[g][rt][e] = 0.f;

    for (int i = 0; i < iters; ++i) {
        #pragma unroll
        for (int s = 0; s < 4; ++s)
            *(half8_t*)&sA[srow0 + s * 16][grp * 8] =
                *(const half8_t*)(arow + (size_t)s * 16 * SROW + i * 64);
        __syncthreads();
        #pragma unroll
        for (int ks = 0; ks < 2; ++ks) {
            half8_t af[4], bf[4];
            #pragma unroll
            for (int g = 0; g < 4; ++g)
                bf[g] = *(const half8_t*)(wptr + (ks * 4 + g) * 1024);
            #pragma unroll
            for (int rt = 0; rt < 4; ++rt)
                af[rt] = *(const half8_t*)&sA[rt * 16 + lr][kh * 64 + ks * 32 + lq * 8];
            #pragma unroll
            for (int g = 0; g < 4; ++g)
                #pragma unroll
                for (int rt = 0; rt < 4; ++rt)
                    acc[g][rt] = __builtin_amdgcn_mfma_f32_16x16x32_f16(
                        af[rt], bf[g], acc[g][rt], 0, 0, 0);
        }
        wptr += 8192;
        __syncthreads();
    }

    // split-K combine (2 rounds x 2 gates, 16 KB scratch in sA)
    float* scr = (float*)&sA[0][0];
    #pragma unroll
    for (int gp = 0; gp < 2; ++gp) {
        if (kh == 1) {
            #pragma unroll
            for (int g2 = 0; g2 < 2; ++g2)
                #pragma unroll
                for (int rt = 0; rt < 4; ++rt) {
                    int slot = ((hw * 2 + g2) * 4 + rt) * 64 + lane;
                    *(float4_t*)&scr[slot * 4] = acc[gp * 2 + g2][rt];
                }
        }
        __syncthreads();
        if (kh == 0) {
            #pragma unroll
            for (int g2 = 0; g2 < 2; ++g2)
                #pragma unroll
                for (int rt = 0; rt < 4; ++rt) {
                    int slot = ((hw * 2 + g2) * 4 + rt) * 64 + lane;
                    acc[gp * 2 + g2][rt] += *(const float4_t*)&scr[slot * 4];
                }
        }
        __syncthreads();
    }
    if (kh != 0) return;

    const int j = h0 + hw * 16 + lr;
    const float bi = bias[j], bff = bias[1024 + j];
    const float bg = bias[2048 + j], bo = bias[3072 + j];
    #pragma unroll
    for (int rt = 0; rt < 4; ++rt) {
        #pragma unroll
        for (int e = 0; e < 4; ++e) {
            const int brow = m0 + rt * 16 + lq * 4 + e;
            float gi = sigmoid_f(acc[0][rt][e] + bi);
            float gf = sigmoid_f(acc[1][rt][e] + bff);
            float gg = tanh_f(acc[2][rt][e] + bg);
            float go = sigmoid_f(acc[3][rt][e] + bo);
            const size_t ci = (size_t)brow * 1024 + j;
            float cn = gf * cvec[ci] + gi * gg;
            cvec[ci] = cn;
            hdst[(size_t)brow * SROW + j] = (_Float16)(go * tanh_f(cn));
        }
    }
}

// out-proj: 64x64x1024 fp16 MFMA; block tile 64 batch x 32 i; 1 "gate".
__device__ __forceinline__ void proj_body(_Float16 (*sA)[136],
    const _Float16* __restrict__ A, const _Float16* __restrict__ Wp,
    const float* __restrict__ blin, float* __restrict__ outp,
    _Float16* __restrict__ xdst, const int unit)
{
    const int iters = 8, Ksh = 16;
    const int tid = threadIdx.x;
    const int lane = tid & 63, w = tid >> 6;
    const int hw = w & 1, kh = w >> 1;
    const int lr = lane & 15, lq = lane >> 4;
    const int ht = unit & 1, mt = unit >> 1;
    const int h0 = ht * 32, m0 = mt * 64;
    const int hgrp = ht * 2 + hw;

    const char* wptr = (const char*)Wp
        + ((size_t)hgrp * (2 * Ksh) + (size_t)kh * Ksh) * 1024
        + (size_t)lane * 16;

    const int srow0 = tid >> 4, grp = tid & 15;
    const _Float16* abase = A + (grp >> 3) * 512 + (size_t)(grp & 7) * 8;
    const _Float16* arow = abase + (size_t)(m0 + srow0) * SROW;

    float4_t acc[4];
    #pragma unroll
    for (int rt = 0; rt < 4; ++rt)
        #pragma unroll
        for (int e = 0; e < 4; ++e) acc[rt][e] = 0.f;

    for (int i = 0; i < iters; ++i) {
        #pragma unroll
        for (int s = 0; s < 4; ++s)
            *(half8_t*)&sA[srow0 + s * 16][grp * 8] =
                *(const half8_t*)(arow + (size_t)s * 16 * SROW + i * 64);
        __syncthreads();
        #pragma unroll
        for (int ks = 0; ks < 2; ++ks) {
            half8_t af[4], bf;
            bf = *(const half8_t*)(wptr + ks * 1024);
            #pragma unroll
            for (int rt = 0; rt < 4; ++rt)
                af[rt] = *(const half8_t*)&sA[rt * 16 + lr][kh * 64 + ks * 32 + lq * 8];
            #pragma unroll
            for (int rt = 0; rt < 4; ++rt)
                acc[rt] = __builtin_amdgcn_mfma_f32_16x16x32_f16(
                    af[rt], bf, acc[rt], 0, 0, 0);
        }
        wptr += 2048;
        __syncthreads();
    }

    float* scr = (float*)&sA[0][0];
    if (kh == 1) {
        #pragma unroll
        for (int rt = 0; rt < 4; ++rt) {
            int slot = (hw * 4 + rt) * 64 + lane;
            *(float4_t*)&scr[slot * 4] = acc[rt];
        }
    }
    __syncthreads();
    if (kh != 0) return;
    #pragma unroll
    for (int rt = 0; rt < 4; ++rt) {
        int slot = (hw * 4 + rt) * 64 + lane;
        acc[rt] += *(const float4_t*)&scr[slot * 4];
    }

    const int j = h0 + hw * 16 + lr;
    const float bj = blin[j];
    #pragma unroll
    for (int rt = 0; rt < 4; ++rt) {
        #pragma unroll
        for (int e = 0; e < 4; ++e) {
            const int brow = m0 + rt * 16 + lq * 4 + e;
            float s = acc[rt][e] + bj;
            outp[(size_t)brow * (NST_ * I_) + j] = s;
            if (xdst) xdst[(size_t)brow * SROW + j] = (_Float16)s;
        }
    }
}

// ---------------- fused multi-role dispatch --------------------------------
struct StepArgs {
    int nL2, nL1, nProj, nCopy;
    const _Float16 *l2Alo, *l2Ahi; _Float16* l2H; float* c2;
    const _Float16 *l1Alo, *l1Ahi; _Float16* l1H; float* c1;
    const _Float16* pA; float* pOut; _Float16* pXdst;
    const float* xsrc; _Float16* xdst;
    const _Float16 *W1p, *W2p, *Wlp;
    const float *b1, *b2, *blin;
};

__global__ __launch_bounds__(256, 4) void fused_step(StepArgs a) {
    __shared__ __align__(16) _Float16 sA[64][136];
    int bid = blockIdx.x;
    if (bid < a.nL2) {
        gemm_body(sA, a.l2Alo, a.l2Ahi, a.W2p, 16, 32, a.b2, a.c2, a.l2H, bid);
    } else if ((bid -= a.nL2) < a.nL1) {
        gemm_body(sA, a.l1Alo, a.l1Ahi, a.W1p, 9, 18, a.b1, a.c1, a.l1H, bid);
    } else if ((bid -= a.nL1) < a.nProj) {
        proj_body(sA, a.pA, a.Wlp, a.blin, a.pOut, a.pXdst, bid);
    } else {
        bid -= a.nProj;
        int base = bid * 256 + threadIdx.x;
        for (int k = base; k < B_ * I_; k += a.nCopy * 256) {
            int b = k >> 6, i = k & 63;
            a.xdst[(size_t)b * SROW + i] = (_Float16)a.xsrc[(size_t)b * (T_ * I_) + i];
        }
    }
}

// ---------------------------------------------------------------------------
extern "C" void kernel_launch(void* const* d_in, const int* in_sizes, int n_in,
                              void* d_out, int out_size, void* d_ws, size_t ws_size,
                              hipStream_t stream) {
    (void)in_sizes; (void)n_in; (void)out_size; (void)ws_size;
    const float* x    = (const float*)d_in[0];
    const float* Wih1 = (const float*)d_in[1];
    const float* Whh1 = (const float*)d_in[2];
    const float* bih1 = (const float*)d_in[3];
    const float* bhh1 = (const float*)d_in[4];
    const float* Wih2 = (const float*)d_in[5];
    const float* Whh2 = (const float*)d_in[6];
    const float* bih2 = (const float*)d_in[7];
    const float* bhh2 = (const float*)d_in[8];
    const float* Wlin = (const float*)d_in[9];
    const float* blin = (const float*)d_in[10];
    float* out = (float*)d_out;

    char* p = (char*)d_ws;
    auto alloc = [&](size_t bytes) {
        char* r = p; p += (bytes + 255) & ~(size_t)255; return r;
    };
    _Float16* W1p = (_Float16*)alloc((size_t)4096 * 1152 * 2);
    _Float16* W2p = (_Float16*)alloc((size_t)4096 * 2048 * 2);
    _Float16* Wlp = (_Float16*)alloc((size_t)64 * 1024 * 2);
    _Float16* S[3];
    for (int i = 0; i < 3; ++i) S[i] = (_Float16*)alloc((size_t)B_ * SROW * 2);
    float* c1 = (float*)alloc((size_t)B_ * H_ * 4);
    float* c2 = (float*)alloc((size_t)B_ * H_ * 4);
    float* b1 = (float*)alloc(4096 * 4);
    float* b2 = (float*)alloc(4096 * 4);

    for (int i = 0; i < 3; ++i)
        hipMemsetAsync(S[i], 0, (size_t)B_ * SROW * 2, stream);
    hipMemsetAsync(c1, 0, (size_t)B_ * H_ * 4, stream);
    hipMemsetAsync(c2, 0, (size_t)B_ * H_ * 4, stream);

    {
        const size_t total = 589824 + 1048576 + 8192 + 65536 + 65536 + 8192;
        convert_all<<<(int)((total + 255) / 256), 256, 0, stream>>>(
            x, Wih1, Whh1, bih1, bhh1, Wih2, Whh2, bih2, bhh2, Wlin,
            W1p, W2p, Wlp, S[0] + 1024, S[1] + 1024, b1, b2);
    }

    StepArgs a{};
    a.W1p = W1p; a.W2p = W2p; a.Wlp = Wlp;
    a.b1 = b1; a.b2 = b2; a.blin = blin;
    a.c1 = c1; a.c2 = c2;

    // prologue: L1(0) alone (reads S[0] = [0|x(0)], writes h1(0) -> S[1])
    {
        StepArgs q = a;
        q.nL2 = 0; q.nL1 = 512; q.nProj = 0; q.nCopy = 0;
        q.l1Alo = S[0]; q.l1Ahi = S[0] + 576; q.l1H = S[1];
        fused_step<<<512, 256, 0, stream>>>(q);
    }

    // main phase: D_t = {L2(t), L1(t+1), proj(t-1), xcopy(t+2)}
    for (int t = 0; t <= 62; ++t) {
        _Float16* Sp = S[t % 3];
        _Float16* Sq = S[(t + 1) % 3];
        _Float16* Sn = S[(t + 2) % 3];
        StepArgs q = a;
        q.nL2 = 512; q.nL1 = 512;
        q.nProj = (t >= 1) ? 32 : 0;
        q.nCopy = (t <= 61) ? 16 : 0;
        q.l2Alo = Sq; q.l2Ahi = Sp + 1152; q.l2H = Sq + 1152;
        q.l1Alo = Sq; q.l1Ahi = Sq + 576; q.l1H = Sn;
        q.pA = Sp + 1152; q.pOut = out + (size_t)(t - 1) * I_; q.pXdst = nullptr;
        q.xsrc = x + (size_t)(t + 2) * I_; q.xdst = Sn + 1024;
        int grid = q.nL2 + q.nL1 + q.nProj + q.nCopy;
        fused_step<<<grid, 256, 0, stream>>>(q);
    }

    // t=63: {L2(63), proj(62)}, then {proj(63) + x(64) feedback}
    {
        StepArgs q = a;
        q.nL2 = 512; q.nL1 = 0; q.nProj = 32; q.nCopy = 0;
        q.l2Alo = S[1]; q.l2Ahi = S[0] + 1152; q.l2H = S[1] + 1152;
        q.pA = S[0] + 1152; q.pOut = out + (size_t)62 * I_; q.pXdst = nullptr;
        fused_step<<<544, 256, 0, stream>>>(q);
    }
    {
        StepArgs q = a;
        q.nL2 = 0; q.nL1 = 0; q.nProj = 32; q.nCopy = 0;
        q.pA = S[1] + 1152; q.pOut = out + (size_t)63 * I_; q.pXdst = S[1] + 1024;
        fused_step<<<32, 256, 0, stream>>>(q);
    }

    // future phase: serial L1(t) -> L2(t) -> proj(t)
    for (int t = T_; t < NST_; ++t) {
        _Float16* Sp = S[t % 3];
        _Float16* Sq = S[(t + 1) % 3];
        {
            StepArgs q = a;
            q.nL2 = 0; q.nL1 = 512; q.nProj = 0; q.nCopy = 0;
            q.l1Alo = Sp; q.l1Ahi = Sp + 576; q.l1H = Sq;
            fused_step<<<512, 256, 0, stream>>>(q);
        }
        {
            StepArgs q = a;
            q.nL2 = 512; q.nL1 = 0; q.nProj = 0; q.nCopy = 0;
            q.l2Alo = Sq; q.l2Ahi = Sp + 1152; q.l2H = Sq + 1152;
            fused_step<<<512, 256, 0, stream>>>(q);
        }
        {
            StepArgs q = a;
            q.nL2 = 0; q.nL1 = 0; q.nProj = 32; q.nCopy = 0;
            q.pA = Sq + 1152; q.pOut = out + (size_t)t * I_;
            q.pXdst = (t + 1 < NST_) ? (Sq + 1024) : nullptr;
            fused_step<<<32, 256, 0, stream>>>(q);
        }
    }
}

// Round 4
// 3686.204 us; speedup vs baseline: 2.0903x; 1.0229x over previous
//
#include <hip/hip_runtime.h>

// TrajLSTM: 2-layer LSTM (H=1024) over T=64 steps + 16 autoregressive steps.
// B=1024, I=64. fp16 MFMA GEMMs, fused LSTM-cell epilogue, fp16-MFMA out-proj.
//
// State rows (fp16, stride 2176): [h1(1024) | x(64) | pad(64) | h2(1024)],
// three buffers rotating by t%3; one fused dispatch = {L2(t), L1(t+1),
// proj(t-1), xcopy(t+2)} (mutually independent). Future phase is serial.
//
// Round 4:
//  - XCD weight pinning: unit->(ht,mt) with ht = (u%8)*4 + (u>>3)%4 so each
//    XCD (bid%8 round-robin) always touches the same 3.2 MB weight slice ->
//    stays resident in its 4 MB L2 across all dispatches.
//  - A staged via global_load_lds (async DMA, dest = wave base + lane*16),
//    XOR-granule swizzle (phys granule p = g ^ (row&15)) -> conflict-free
//    af reads with NO row padding (padding would break the DMA layout).
//  - bf (weights) register-prefetched one K-iter ahead; launch_bounds(256,3).

#define B_   1024
#define T_   64
#define I_   64
#define H_   1024
#define FUT_ 16
#define NST_ (T_ + FUT_)
#define SROW 2176

typedef _Float16 half8_t  __attribute__((ext_vector_type(8)));
typedef float    float4_t __attribute__((ext_vector_type(4)));

typedef __attribute__((address_space(1))) const unsigned int g_u32;
typedef __attribute__((address_space(3))) unsigned int l_u32;

__device__ __forceinline__ void load_lds16(const _Float16* g, _Float16* l) {
    __builtin_amdgcn_global_load_lds((g_u32*)g, (l_u32*)l, 16, 0, 0);
}

__device__ __forceinline__ float sigmoid_f(float x) {
    x = fminf(fmaxf(x, -30.f), 30.f);
    return __fdividef(1.f, 1.f + __expf(-x));
}
__device__ __forceinline__ float tanh_f(float x) {
    x = fminf(fmaxf(x, -15.f), 15.f);
    float e = __expf(2.f * x);
    return 1.f - 2.f * __fdividef(1.f, e + 1.f);
}

// ---------------- one-time conversion / packing ----------------------------
// W1p: [hgrp 64][kstep 36][gate 4][1KB]  (logical K=1152: h1|x|pad0)
// W2p: [hgrp 64][kstep 64][gate 4][1KB]  (logical K=2048: h1'|h2)
// Wlp: [hgrp 4 ][kstep 32][1KB]          (64 x 1024)
__global__ void convert_all(const float* __restrict__ x,
    const float* __restrict__ Wih1, const float* __restrict__ Whh1,
    const float* __restrict__ bih1, const float* __restrict__ bhh1,
    const float* __restrict__ Wih2, const float* __restrict__ Whh2,
    const float* __restrict__ bih2, const float* __restrict__ bhh2,
    const float* __restrict__ Wlin,
    _Float16* __restrict__ W1p, _Float16* __restrict__ W2p,
    _Float16* __restrict__ Wlp,
    _Float16* __restrict__ S0x, _Float16* __restrict__ S1x,
    float* __restrict__ b1, float* __restrict__ b2)
{
    size_t idx = (size_t)blockIdx.x * 256 + threadIdx.x;
    const size_t nc1 = 589824;    // 4096*1152/8
    const size_t nc2 = 1048576;   // 4096*2048/8
    const size_t nc3 = 8192;      // 64*1024/8
    const size_t nx  = 65536;     // B_*I_
    if (idx < nc1) {
        int c = (int)idx;
        int lane = c & 63, g = (c >> 6) & 3, rem = c >> 8;
        int j = rem % 36, hgrp = rem / 36;
        int row = (g << 10) + hgrp * 16 + (lane & 15);
        int kb = j * 32 + (lane >> 4) * 8;
        _Float16* o = &W1p[(size_t)c * 8];
        if (kb < 1024) {
            #pragma unroll
            for (int i = 0; i < 8; ++i) o[i] = (_Float16)Whh1[(size_t)row * 1024 + kb + i];
        } else if (kb < 1088) {
            #pragma unroll
            for (int i = 0; i < 8; ++i) o[i] = (_Float16)Wih1[row * 64 + (kb - 1024) + i];
        } else {
            #pragma unroll
            for (int i = 0; i < 8; ++i) o[i] = (_Float16)0.f;
        }
    } else if ((idx -= nc1) < nc2) {
        int c = (int)idx;
        int lane = c & 63, g = (c >> 6) & 3, rem = c >> 8;
        int j = rem & 63, hgrp = rem >> 6;
        int row = (g << 10) + hgrp * 16 + (lane & 15);
        int kb = j * 32 + (lane >> 4) * 8;
        _Float16* o = &W2p[(size_t)c * 8];
        if (kb < 1024) {
            #pragma unroll
            for (int i = 0; i < 8; ++i) o[i] = (_Float16)Wih2[(size_t)row * 1024 + kb + i];
        } else {
            #pragma unroll
            for (int i = 0; i < 8; ++i) o[i] = (_Float16)Whh2[(size_t)row * 1024 + kb - 1024 + i];
        }
    } else if ((idx -= nc2) < nc3) {
        int c = (int)idx;
        int lane = c & 63, j = (c >> 6) & 31, hgrp = c >> 11;
        int row = hgrp * 16 + (lane & 15);
        int kb = j * 32 + (lane >> 4) * 8;
        _Float16* o = &Wlp[(size_t)c * 8];
        #pragma unroll
        for (int i = 0; i < 8; ++i) o[i] = (_Float16)Wlin[(size_t)row * 1024 + kb + i];
    } else if ((idx -= nc3) < nx) {
        int b = (int)(idx >> 6), i = (int)(idx & 63);
        S0x[(size_t)b * SROW + i] = (_Float16)x[(size_t)b * (T_ * I_) + i];
    } else if ((idx -= nx) < nx) {
        int b = (int)(idx >> 6), i = (int)(idx & 63);
        S1x[(size_t)b * SROW + i] = (_Float16)x[(size_t)b * (T_ * I_) + 64 + i];
    } else if ((idx -= nx) < 4096) {
        b1[idx] = bih1[idx] + bhh1[idx];
    } else if ((idx -= 4096) < 4096) {
        b2[idx] = bih2[idx] + bhh2[idx];
    }
}

// ---------------- GEMM + fused LSTM cell -----------------------------------
// Block tile: 64 batch x 32 H x 4 gates; 4 waves = 2 hw (H) x 2 kh (split-K).
// sA: 64 rows x 128 halves (16 KB, no pad); granule (16B) swizzle p=g^(row&15).
__device__ __forceinline__ void gemm_body(_Float16* sA,
    const _Float16* __restrict__ Alo, const _Float16* __restrict__ Ahi,
    const _Float16* __restrict__ Wp, const int iters, const int Ksh,
    const float* __restrict__ bias, float* __restrict__ cvec,
    _Float16* __restrict__ hdst, const int unit)
{
    const int tid = threadIdx.x;
    const int lane = tid & 63, w = tid >> 6;
    const int hw = w & 1, kh = w >> 1;
    const int lr = lane & 15, lq = lane >> 4;
    const int ht = ((unit & 7) << 2) | ((unit >> 3) & 3);   // XCD-pinned H tile
    const int mt = unit >> 5;
    const int h0 = ht * 32, m0 = mt * 64;
    const int hgrp = ht * 2 + hw;

    const char* wptr = (const char*)Wp
        + ((size_t)hgrp * (2 * Ksh) + (size_t)kh * Ksh) * 4096
        + (size_t)lane * 16;

    // staging: thread t -> rows (t>>4)+s*16, phys granule p=t&15,
    // logical granule gg = p ^ (row&15); source offset = (gg&7)*16B in K-half
    const int srow0 = tid >> 4, pg = tid & 15;
    const int gg = pg ^ (srow0 & 15);
    const _Float16* asrc = (gg < 8 ? Alo : Ahi) + (gg & 7) * 8
                         + (size_t)(m0 + srow0) * SROW;
    _Float16* ldst = sA + tid * 8;

    // af read offsets (halves): row*128 + ((kh*8 + ks*4 + lq) ^ lr)*8
    const int ag0 = ((kh * 8 + lq) ^ lr) * 8;
    const int ag1 = ((kh * 8 + 4 + lq) ^ lr) * 8;

    float4_t acc[4][4];
    #pragma unroll
    for (int g = 0; g < 4; ++g)
        #pragma unroll
        for (int rt = 0; rt < 4; ++rt)
            #pragma unroll
            for (int e = 0; e < 4; ++e) acc[g][rt][e] = 0.f;

    half8_t bfc[8], bfn[8];
    #pragma unroll
    for (int q = 0; q < 8; ++q)
        bfc[q] = *(const half8_t*)(wptr + q * 1024);

    for (int i = 0; i < iters; ++i) {
        // async DMA A tile for this iter (64 rows x 128 halves)
        #pragma unroll
        for (int s = 0; s < 4; ++s)
            load_lds16(asrc + (size_t)(srow0 + s * 16 - srow0) * 0 /*kept simple*/
                       + (size_t)s * 16 * SROW + (size_t)i * 64,
                       ldst + s * 2048);
        __syncthreads();   // DMA visible + previous readers done

        if (i + 1 < iters) {
            const char* wn = wptr + 8192;
            #pragma unroll
            for (int q = 0; q < 8; ++q)
                bfn[q] = *(const half8_t*)(wn + q * 1024);
        }
        #pragma unroll
        for (int ks = 0; ks < 2; ++ks) {
            const int ag = ks ? ag1 : ag0;
            half8_t af[4];
            #pragma unroll
            for (int rt = 0; rt < 4; ++rt)
                af[rt] = *(const half8_t*)&sA[(rt * 16 + lr) * 128 + ag];
            #pragma unroll
            for (int g = 0; g < 4; ++g)
                #pragma unroll
                for (int rt = 0; rt < 4; ++rt)
                    acc[g][rt] = __builtin_amdgcn_mfma_f32_16x16x32_f16(
                        af[rt], bfc[ks * 4 + g], acc[g][rt], 0, 0, 0);
        }
        __syncthreads();   // readers done before next DMA overwrites sA
        wptr += 8192;
        #pragma unroll
        for (int q = 0; q < 8; ++q) bfc[q] = bfn[q];
    }

    // split-K combine through LDS (2 rounds x 2 gates, 16 KB scratch)
    float* scr = (float*)sA;
    #pragma unroll
    for (int gp = 0; gp < 2; ++gp) {
        if (kh == 1) {
            #pragma unroll
            for (int g2 = 0; g2 < 2; ++g2)
                #pragma unroll
                for (int rt = 0; rt < 4; ++rt) {
                    int slot = ((hw * 2 + g2) * 4 + rt) * 64 + lane;
                    *(float4_t*)&scr[slot * 4] = acc[gp * 2 + g2][rt];
                }
        }
        __syncthreads();
        if (kh == 0) {
            #pragma unroll
            for (int g2 = 0; g2 < 2; ++g2)
                #pragma unroll
                for (int rt = 0; rt < 4; ++rt) {
                    int slot = ((hw * 2 + g2) * 4 + rt) * 64 + lane;
                    acc[gp * 2 + g2][rt] += *(const float4_t*)&scr[slot * 4];
                }
        }
        __syncthreads();
    }
    if (kh != 0) return;

    const int j = h0 + hw * 16 + lr;
    const float bi = bias[j], bff = bias[1024 + j];
    const float bg = bias[2048 + j], bo = bias[3072 + j];
    #pragma unroll
    for (int rt = 0; rt < 4; ++rt) {
        #pragma unroll
        for (int e = 0; e < 4; ++e) {
            const int brow = m0 + rt * 16 + lq * 4 + e;
            float gi = sigmoid_f(acc[0][rt][e] + bi);
            float gf = sigmoid_f(acc[1][rt][e] + bff);
            float gv = tanh_f(acc[2][rt][e] + bg);
            float go = sigmoid_f(acc[3][rt][e] + bo);
            const size_t ci = (size_t)brow * 1024 + j;
            float cn = gf * cvec[ci] + gi * gv;
            cvec[ci] = cn;
            hdst[(size_t)brow * SROW + j] = (_Float16)(go * tanh_f(cn));
        }
    }
}

// out-proj: 64 batch x 32 i tile, K=1024 fp16 MFMA, same staging scheme.
__device__ __forceinline__ void proj_body(_Float16* sA,
    const _Float16* __restrict__ A, const _Float16* __restrict__ Wp,
    const float* __restrict__ blin, float* __restrict__ outp,
    _Float16* __restrict__ xdst, const int unit)
{
    const int iters = 8;
    const int tid = threadIdx.x;
    const int lane = tid & 63, w = tid >> 6;
    const int hw = w & 1, kh = w >> 1;
    const int lr = lane & 15, lq = lane >> 4;
    const int ht = unit & 1, mt = unit >> 1;
    const int h0 = ht * 32, m0 = mt * 64;
    const int hgrp = ht * 2 + hw;

    const char* wptr = (const char*)Wp
        + ((size_t)hgrp * 32 + (size_t)kh * 16) * 1024 + (size_t)lane * 16;

    const int srow0 = tid >> 4, pg = tid & 15;
    const int gg = pg ^ (srow0 & 15);
    const _Float16* asrc = A + (size_t)(gg >> 3) * 512 + (gg & 7) * 8
                         + (size_t)(m0 + srow0) * SROW;
    _Float16* ldst = sA + tid * 8;
    const int ag0 = ((kh * 8 + lq) ^ lr) * 8;
    const int ag1 = ((kh * 8 + 4 + lq) ^ lr) * 8;

    float4_t acc[4];
    #pragma unroll
    for (int rt = 0; rt < 4; ++rt)
        #pragma unroll
        for (int e = 0; e < 4; ++e) acc[rt][e] = 0.f;

    half8_t b0 = *(const half8_t*)(wptr);
    half8_t b1v = *(const half8_t*)(wptr + 1024);
    for (int i = 0; i < iters; ++i) {
        #pragma unroll
        for (int s = 0; s < 4; ++s)
            load_lds16(asrc + (size_t)s * 16 * SROW + (size_t)i * 64,
                       ldst + s * 2048);
        __syncthreads();
        half8_t n0, n1;
        if (i + 1 < iters) {
            n0 = *(const half8_t*)(wptr + 2048);
            n1 = *(const half8_t*)(wptr + 3072);
        }
        half8_t af;
        #pragma unroll
        for (int rt = 0; rt < 4; ++rt) {
            af = *(const half8_t*)&sA[(rt * 16 + lr) * 128 + ag0];
            acc[rt] = __builtin_amdgcn_mfma_f32_16x16x32_f16(af, b0, acc[rt], 0, 0, 0);
        }
        #pragma unroll
        for (int rt = 0; rt < 4; ++rt) {
            af = *(const half8_t*)&sA[(rt * 16 + lr) * 128 + ag1];
            acc[rt] = __builtin_amdgcn_mfma_f32_16x16x32_f16(af, b1v, acc[rt], 0, 0, 0);
        }
        __syncthreads();
        wptr += 2048;
        b0 = n0; b1v = n1;
    }

    float* scr = (float*)sA;
    if (kh == 1) {
        #pragma unroll
        for (int rt = 0; rt < 4; ++rt) {
            int slot = (hw * 4 + rt) * 64 + lane;
            *(float4_t*)&scr[slot * 4] = acc[rt];
        }
    }
    __syncthreads();
    if (kh != 0) return;
    #pragma unroll
    for (int rt = 0; rt < 4; ++rt) {
        int slot = (hw * 4 + rt) * 64 + lane;
        acc[rt] += *(const float4_t*)&scr[slot * 4];
    }

    const int j = h0 + hw * 16 + lr;
    const float bj = blin[j];
    #pragma unroll
    for (int rt = 0; rt < 4; ++rt) {
        #pragma unroll
        for (int e = 0; e < 4; ++e) {
            const int brow = m0 + rt * 16 + lq * 4 + e;
            float s = acc[rt][e] + bj;
            outp[(size_t)brow * (NST_ * I_) + j] = s;
            if (xdst) xdst[(size_t)brow * SROW + j] = (_Float16)s;
        }
    }
}

// ---------------- fused multi-role dispatch --------------------------------
struct StepArgs {
    int nL2, nL1, nProj, nCopy;
    const _Float16 *l2Alo, *l2Ahi; _Float16* l2H; float* c2;
    const _Float16 *l1Alo, *l1Ahi; _Float16* l1H; float* c1;
    const _Float16* pA; float* pOut; _Float16* pXdst;
    const float* xsrc; _Float16* xdst;
    const _Float16 *W1p, *W2p, *Wlp;
    const float *b1, *b2, *blin;
};

__global__ __launch_bounds__(256, 3) void fused_step(StepArgs a) {
    __shared__ __align__(16) _Float16 sA[8192];   // 16 KB
    int bid = blockIdx.x;
    if (bid < a.nL2) {
        gemm_body(sA, a.l2Alo, a.l2Ahi, a.W2p, 16, 32, a.b2, a.c2, a.l2H, bid);
    } else if ((bid -= a.nL2) < a.nL1) {
        gemm_body(sA, a.l1Alo, a.l1Ahi, a.W1p, 9, 18, a.b1, a.c1, a.l1H, bid);
    } else if ((bid -= a.nL1) < a.nProj) {
        proj_body(sA, a.pA, a.Wlp, a.blin, a.pOut, a.pXdst, bid);
    } else {
        bid -= a.nProj;
        int base = bid * 256 + threadIdx.x;
        for (int k = base; k < B_ * I_; k += a.nCopy * 256) {
            int b = k >> 6, i = k & 63;
            a.xdst[(size_t)b * SROW + i] = (_Float16)a.xsrc[(size_t)b * (T_ * I_) + i];
        }
    }
}

// ---------------------------------------------------------------------------
extern "C" void kernel_launch(void* const* d_in, const int* in_sizes, int n_in,
                              void* d_out, int out_size, void* d_ws, size_t ws_size,
                              hipStream_t stream) {
    (void)in_sizes; (void)n_in; (void)out_size; (void)ws_size;
    const float* x    = (const float*)d_in[0];
    const float* Wih1 = (const float*)d_in[1];
    const float* Whh1 = (const float*)d_in[2];
    const float* bih1 = (const float*)d_in[3];
    const float* bhh1 = (const float*)d_in[4];
    const float* Wih2 = (const float*)d_in[5];
    const float* Whh2 = (const float*)d_in[6];
    const float* bih2 = (const float*)d_in[7];
    const float* bhh2 = (const float*)d_in[8];
    const float* Wlin = (const float*)d_in[9];
    const float* blin = (const float*)d_in[10];
    float* out = (float*)d_out;

    char* p = (char*)d_ws;
    auto alloc = [&](size_t bytes) {
        char* r = p; p += (bytes + 255) & ~(size_t)255; return r;
    };
    _Float16* W1p = (_Float16*)alloc((size_t)4096 * 1152 * 2);
    _Float16* W2p = (_Float16*)alloc((size_t)4096 * 2048 * 2);
    _Float16* Wlp = (_Float16*)alloc((size_t)64 * 1024 * 2);
    _Float16* S[3];
    for (int i = 0; i < 3; ++i) S[i] = (_Float16*)alloc((size_t)B_ * SROW * 2);
    float* c1 = (float*)alloc((size_t)B_ * H_ * 4);
    float* c2 = (float*)alloc((size_t)B_ * H_ * 4);
    float* b1 = (float*)alloc(4096 * 4);
    float* b2 = (float*)alloc(4096 * 4);

    for (int i = 0; i < 3; ++i)
        hipMemsetAsync(S[i], 0, (size_t)B_ * SROW * 2, stream);
    hipMemsetAsync(c1, 0, (size_t)B_ * H_ * 4, stream);
    hipMemsetAsync(c2, 0, (size_t)B_ * H_ * 4, stream);

    {
        const size_t total = 589824 + 1048576 + 8192 + 65536 + 65536 + 8192;
        convert_all<<<(int)((total + 255) / 256), 256, 0, stream>>>(
            x, Wih1, Whh1, bih1, bhh1, Wih2, Whh2, bih2, bhh2, Wlin,
            W1p, W2p, Wlp, S[0] + 1024, S[1] + 1024, b1, b2);
    }

    StepArgs a{};
    a.W1p = W1p; a.W2p = W2p; a.Wlp = Wlp;
    a.b1 = b1; a.b2 = b2; a.blin = blin;
    a.c1 = c1; a.c2 = c2;

    // prologue: L1(0) alone
    {
        StepArgs q = a;
        q.nL2 = 0; q.nL1 = 512; q.nProj = 0; q.nCopy = 0;
        q.l1Alo = S[0]; q.l1Ahi = S[0] + 576; q.l1H = S[1];
        fused_step<<<512, 256, 0, stream>>>(q);
    }

    // main phase: D_t = {L2(t), L1(t+1), proj(t-1), xcopy(t+2)}
    for (int t = 0; t <= 62; ++t) {
        _Float16* Sp = S[t % 3];
        _Float16* Sq = S[(t + 1) % 3];
        _Float16* Sn = S[(t + 2) % 3];
        StepArgs q = a;
        q.nL2 = 512; q.nL1 = 512;
        q.nProj = (t >= 1) ? 32 : 0;
        q.nCopy = (t <= 61) ? 16 : 0;
        q.l2Alo = Sq; q.l2Ahi = Sp + 1152; q.l2H = Sq + 1152;
        q.l1Alo = Sq; q.l1Ahi = Sq + 576; q.l1H = Sn;
        q.pA = Sp + 1152; q.pOut = out + (size_t)(t - 1) * I_; q.pXdst = nullptr;
        q.xsrc = x + (size_t)(t + 2) * I_; q.xdst = Sn + 1024;
        int grid = q.nL2 + q.nL1 + q.nProj + q.nCopy;
        fused_step<<<grid, 256, 0, stream>>>(q);
    }

    // t=63: {L2(63), proj(62)}, then {proj(63) + x(64) feedback}
    {
        StepArgs q = a;
        q.nL2 = 512; q.nL1 = 0; q.nProj = 32; q.nCopy = 0;
        q.l2Alo = S[1]; q.l2Ahi = S[0] + 1152; q.l2H = S[1] + 1152;
        q.pA = S[0] + 1152; q.pOut = out + (size_t)62 * I_; q.pXdst = nullptr;
        fused_step<<<544, 256, 0, stream>>>(q);
    }
    {
        StepArgs q = a;
        q.nL2 = 0; q.nL1 = 0; q.nProj = 32; q.nCopy = 0;
        q.pA = S[1] + 1152; q.pOut = out + (size_t)63 * I_; q.pXdst = S[1] + 1024;
        fused_step<<<32, 256, 0, stream>>>(q);
    }

    // future phase: serial L1(t) -> L2(t) -> proj(t)
    for (int t = T_; t < NST_; ++t) {
        _Float16* Sp = S[t % 3];
        _Float16* Sq = S[(t + 1) % 3];
        {
            StepArgs q = a;
            q.nL2 = 0; q.nL1 = 512; q.nProj = 0; q.nCopy = 0;
            q.l1Alo = Sp; q.l1Ahi = Sp + 576; q.l1H = Sq;
            fused_step<<<512, 256, 0, stream>>>(q);
        }
        {
            StepArgs q = a;
            q.nL2 = 512; q.nL1 = 0; q.nProj = 0; q.nCopy = 0;
            q.l2Alo = Sq; q.l2Ahi = Sp + 1152; q.l2H = Sq + 1152;
            fused_step<<<512, 256, 0, stream>>>(q);
        }
        {
            StepArgs q = a;
            q.nL2 = 0; q.nL1 = 0; q.nProj = 32; q.nCopy = 0;
            q.pA = Sq + 1152; q.pOut = out + (size_t)t * I_;
            q.pXdst = (t + 1 < NST_) ? (Sq + 1024) : nullptr;
            fused_step<<<32, 256, 0, stream>>>(q);
        }
    }
}

// Round 5
// 3455.199 us; speedup vs baseline: 2.2301x; 1.0669x over previous
//
#include <hip/hip_runtime.h>

// TrajLSTM: 2-layer LSTM (H=1024) over T=64 steps + 16 autoregressive steps.
// B=1024, I=64. fp16 MFMA GEMMs, fused LSTM-cell epilogue, fp16-MFMA out-proj.
//
// State rows (fp16, stride 2176): [h1(1024) | x(64) | pad(64) | h2(1024)],
// three buffers rotating by t%3; one fused dispatch = {L2(t), L1(t+1),
// proj(t-1), xcopy(t+2)} (mutually independent). Future phase is serial.
//
// Round 5:
//  - m-tile 128 (block = 128 batch x 32 H x 4 gates, 8 row-tiles/wave):
//    64 MFMA per 8KB weight stream per wave (2x arithmetic intensity on B),
//    weight L2 traffic per dispatch halves.
//  - Double-buffered LDS A staging with ONE barrier per K-iter: DMA(i+1)
//    issued right after barrier i into the other buffer, so the compiler's
//    vmcnt(0)-before-s_barrier drain IS the pipeline wait (full compute
//    period in flight for both DMA and bf register prefetch).
//  - XCD weight pinning (ht from bid%8), XOR-granule LDS swizzle (0 bank
//    conflicts, round 4 verified), __launch_bounds__(256,2).

#define B_   1024
#define T_   64
#define I_   64
#define H_   1024
#define FUT_ 16
#define NST_ (T_ + FUT_)
#define SROW 2176

typedef _Float16 half8_t  __attribute__((ext_vector_type(8)));
typedef float    float4_t __attribute__((ext_vector_type(4)));

typedef __attribute__((address_space(1))) const unsigned int g_u32;
typedef __attribute__((address_space(3))) unsigned int l_u32;

__device__ __forceinline__ void load_lds16(const _Float16* g, _Float16* l) {
    __builtin_amdgcn_global_load_lds((g_u32*)g, (l_u32*)l, 16, 0, 0);
}

__device__ __forceinline__ float sigmoid_f(float x) {
    x = fminf(fmaxf(x, -30.f), 30.f);
    return __fdividef(1.f, 1.f + __expf(-x));
}
__device__ __forceinline__ float tanh_f(float x) {
    x = fminf(fmaxf(x, -15.f), 15.f);
    float e = __expf(2.f * x);
    return 1.f - 2.f * __fdividef(1.f, e + 1.f);
}

// ---------------- one-time conversion / packing ----------------------------
// W1p: [hgrp 64][kstep 36][gate 4][1KB]  (logical K=1152: h1|x|pad0)
// W2p: [hgrp 64][kstep 64][gate 4][1KB]  (logical K=2048: h1'|h2)
// Wlp: [hgrp 4 ][kstep 32][1KB]          (64 x 1024)
__global__ void convert_all(const float* __restrict__ x,
    const float* __restrict__ Wih1, const float* __restrict__ Whh1,
    const float* __restrict__ bih1, const float* __restrict__ bhh1,
    const float* __restrict__ Wih2, const float* __restrict__ Whh2,
    const float* __restrict__ bih2, const float* __restrict__ bhh2,
    const float* __restrict__ Wlin,
    _Float16* __restrict__ W1p, _Float16* __restrict__ W2p,
    _Float16* __restrict__ Wlp,
    _Float16* __restrict__ S0x, _Float16* __restrict__ S1x,
    float* __restrict__ b1, float* __restrict__ b2)
{
    size_t idx = (size_t)blockIdx.x * 256 + threadIdx.x;
    const size_t nc1 = 589824;    // 4096*1152/8
    const size_t nc2 = 1048576;   // 4096*2048/8
    const size_t nc3 = 8192;      // 64*1024/8
    const size_t nx  = 65536;     // B_*I_
    if (idx < nc1) {
        int c = (int)idx;
        int lane = c & 63, g = (c >> 6) & 3, rem = c >> 8;
        int j = rem % 36, hgrp = rem / 36;
        int row = (g << 10) + hgrp * 16 + (lane & 15);
        int kb = j * 32 + (lane >> 4) * 8;
        _Float16* o = &W1p[(size_t)c * 8];
        if (kb < 1024) {
            #pragma unroll
            for (int i = 0; i < 8; ++i) o[i] = (_Float16)Whh1[(size_t)row * 1024 + kb + i];
        } else if (kb < 1088) {
            #pragma unroll
            for (int i = 0; i < 8; ++i) o[i] = (_Float16)Wih1[row * 64 + (kb - 1024) + i];
        } else {
            #pragma unroll
            for (int i = 0; i < 8; ++i) o[i] = (_Float16)0.f;
        }
    } else if ((idx -= nc1) < nc2) {
        int c = (int)idx;
        int lane = c & 63, g = (c >> 6) & 3, rem = c >> 8;
        int j = rem & 63, hgrp = rem >> 6;
        int row = (g << 10) + hgrp * 16 + (lane & 15);
        int kb = j * 32 + (lane >> 4) * 8;
        _Float16* o = &W2p[(size_t)c * 8];
        if (kb < 1024) {
            #pragma unroll
            for (int i = 0; i < 8; ++i) o[i] = (_Float16)Wih2[(size_t)row * 1024 + kb + i];
        } else {
            #pragma unroll
            for (int i = 0; i < 8; ++i) o[i] = (_Float16)Whh2[(size_t)row * 1024 + kb - 1024 + i];
        }
    } else if ((idx -= nc2) < nc3) {
        int c = (int)idx;
        int lane = c & 63, j = (c >> 6) & 31, hgrp = c >> 11;
        int row = hgrp * 16 + (lane & 15);
        int kb = j * 32 + (lane >> 4) * 8;
        _Float16* o = &Wlp[(size_t)c * 8];
        #pragma unroll
        for (int i = 0; i < 8; ++i) o[i] = (_Float16)Wlin[(size_t)row * 1024 + kb + i];
    } else if ((idx -= nc3) < nx) {
        int b = (int)(idx >> 6), i = (int)(idx & 63);
        S0x[(size_t)b * SROW + i] = (_Float16)x[(size_t)b * (T_ * I_) + i];
    } else if ((idx -= nx) < nx) {
        int b = (int)(idx >> 6), i = (int)(idx & 63);
        S1x[(size_t)b * SROW + i] = (_Float16)x[(size_t)b * (T_ * I_) + 64 + i];
    } else if ((idx -= nx) < 4096) {
        b1[idx] = bih1[idx] + bhh1[idx];
    } else if ((idx -= 4096) < 4096) {
        b2[idx] = bih2[idx] + bhh2[idx];
    }
}

// ---------------- GEMM + fused LSTM cell -----------------------------------
// Block tile: 128 batch x 32 H x 4 gates; 4 waves = 2 hw (H) x 2 kh (split-K).
// sA: 2 x (128 rows x 128 halves) = 64 KB; granule swizzle p = g ^ (row&15).
__device__ __forceinline__ void gemm_body(_Float16* sAb,
    const _Float16* __restrict__ Alo, const _Float16* __restrict__ Ahi,
    const _Float16* __restrict__ Wp, const int iters, const int Ksh,
    const float* __restrict__ bias, float* __restrict__ cvec,
    _Float16* __restrict__ hdst, const int unit)
{
    const int tid = threadIdx.x;
    const int lane = tid & 63, w = tid >> 6;
    const int hw = w & 1, kh = w >> 1;
    const int lr = lane & 15, lq = lane >> 4;
    const int ht = ((unit & 7) << 2) | ((unit >> 3) & 3);   // XCD-pinned H tile
    const int mt = unit >> 5;                                // 0..7
    const int h0 = ht * 32, m0 = mt * 128;
    const int hgrp = ht * 2 + hw;

    const char* wptr = (const char*)Wp
        + ((size_t)hgrp * (2 * Ksh) + (size_t)kh * Ksh) * 4096
        + (size_t)lane * 16;

    // staging: round s (0..7): thread t -> row (t>>4)+s*16, phys granule t&15.
    // logical granule gg = (t&15) ^ (row&15) (s-invariant since s*16).
    const int srow0 = tid >> 4, pg = tid & 15;
    const int gg = pg ^ (srow0 & 15);
    const _Float16* asrc = (gg < 8 ? Alo : Ahi) + (gg & 7) * 8
                         + (size_t)(m0 + srow0) * SROW;

    // af read offset (halves): row*128 + ((kh*8 + ks*4 + lq) ^ lr)*8
    const int ag0 = ((kh * 8 + lq) ^ lr) * 8;
    const int ag1 = ((kh * 8 + 4 + lq) ^ lr) * 8;

    float4_t acc[4][8];
    #pragma unroll
    for (int g = 0; g < 4; ++g)
        #pragma unroll
        for (int rt = 0; rt < 8; ++rt)
            #pragma unroll
            for (int e = 0; e < 4; ++e) acc[g][rt][e] = 0.f;

    half8_t bfc[8], bfn[8];
    #pragma unroll
    for (int q = 0; q < 8; ++q)
        bfc[q] = *(const half8_t*)(wptr + q * 1024);

    // prologue DMA for iter 0 into buf0
    #pragma unroll
    for (int s = 0; s < 8; ++s)
        load_lds16(asrc + (size_t)s * 16 * SROW, sAb + tid * 8 + s * 2048);

    for (int i = 0; i < iters; ++i) {
        __syncthreads();   // vmcnt(0) drain: DMA(i) + bf(i) complete
        _Float16* cur = sAb + (i & 1) * 16384;
        if (i + 1 < iters) {
            _Float16* nxt = sAb + ((i + 1) & 1) * 16384;
            const _Float16* an = asrc + (size_t)(i + 1) * 64;
            #pragma unroll
            for (int s = 0; s < 8; ++s)
                load_lds16(an + (size_t)s * 16 * SROW, nxt + tid * 8 + s * 2048);
            const char* wn = wptr + 8192;
            #pragma unroll
            for (int q = 0; q < 8; ++q)
                bfn[q] = *(const half8_t*)(wn + q * 1024);
        }
        #pragma unroll
        for (int ks = 0; ks < 2; ++ks) {
            const int ag = ks ? ag1 : ag0;
            #pragma unroll
            for (int rt = 0; rt < 8; ++rt) {
                half8_t af = *(const half8_t*)&cur[(rt * 16 + lr) * 128 + ag];
                #pragma unroll
                for (int g = 0; g < 4; ++g)
                    acc[g][rt] = __builtin_amdgcn_mfma_f32_16x16x32_f16(
                        af, bfc[ks * 4 + g], acc[g][rt], 0, 0, 0);
            }
        }
        wptr += 8192;
        #pragma unroll
        for (int q = 0; q < 8; ++q) bfc[q] = bfn[q];
    }
    __syncthreads();   // all compute done before scratch reuse

    // split-K combine through LDS (2 rounds x 2 gates, 32 KB scratch in buf0)
    float* scr = (float*)sAb;
    #pragma unroll
    for (int gp = 0; gp < 2; ++gp) {
        if (kh == 1) {
            #pragma unroll
            for (int g2 = 0; g2 < 2; ++g2)
                #pragma unroll
                for (int rt = 0; rt < 8; ++rt) {
                    int slot = ((hw * 2 + g2) * 8 + rt) * 64 + lane;
                    *(float4_t*)&scr[slot * 4] = acc[gp * 2 + g2][rt];
                }
        }
        __syncthreads();
        if (kh == 0) {
            #pragma unroll
            for (int g2 = 0; g2 < 2; ++g2)
                #pragma unroll
                for (int rt = 0; rt < 8; ++rt) {
                    int slot = ((hw * 2 + g2) * 8 + rt) * 64 + lane;
                    acc[gp * 2 + g2][rt] += *(const float4_t*)&scr[slot * 4];
                }
        }
        __syncthreads();
    }
    if (kh != 0) return;

    const int j = h0 + hw * 16 + lr;
    const float bi = bias[j], bff = bias[1024 + j];
    const float bg = bias[2048 + j], bo = bias[3072 + j];
    #pragma unroll
    for (int rt = 0; rt < 8; ++rt) {
        #pragma unroll
        for (int e = 0; e < 4; ++e) {
            const int brow = m0 + rt * 16 + lq * 4 + e;
            float gi = sigmoid_f(acc[0][rt][e] + bi);
            float gf = sigmoid_f(acc[1][rt][e] + bff);
            float gv = tanh_f(acc[2][rt][e] + bg);
            float go = sigmoid_f(acc[3][rt][e] + bo);
            const size_t ci = (size_t)brow * 1024 + j;
            float cn = gf * cvec[ci] + gi * gv;
            cvec[ci] = cn;
            hdst[(size_t)brow * SROW + j] = (_Float16)(go * tanh_f(cn));
        }
    }
}

// out-proj: 64 batch x 32 i tile, K=1024 fp16 MFMA (tiny; single-buffer).
__device__ __forceinline__ void proj_body(_Float16* sA,
    const _Float16* __restrict__ A, const _Float16* __restrict__ Wp,
    const float* __restrict__ blin, float* __restrict__ outp,
    _Float16* __restrict__ xdst, const int unit)
{
    const int iters = 8;
    const int tid = threadIdx.x;
    const int lane = tid & 63, w = tid >> 6;
    const int hw = w & 1, kh = w >> 1;
    const int lr = lane & 15, lq = lane >> 4;
    const int ht = unit & 1, mt = unit >> 1;
    const int h0 = ht * 32, m0 = mt * 64;
    const int hgrp = ht * 2 + hw;

    const char* wptr = (const char*)Wp
        + ((size_t)hgrp * 32 + (size_t)kh * 16) * 1024 + (size_t)lane * 16;

    const int srow0 = tid >> 4, pg = tid & 15;
    const int gg = pg ^ (srow0 & 15);
    const _Float16* asrc = A + (size_t)(gg >> 3) * 512 + (gg & 7) * 8
                         + (size_t)(m0 + srow0) * SROW;
    _Float16* ldst = sA + tid * 8;
    const int ag0 = ((kh * 8 + lq) ^ lr) * 8;
    const int ag1 = ((kh * 8 + 4 + lq) ^ lr) * 8;

    float4_t acc[4];
    #pragma unroll
    for (int rt = 0; rt < 4; ++rt)
        #pragma unroll
        for (int e = 0; e < 4; ++e) acc[rt][e] = 0.f;

    half8_t b0 = *(const half8_t*)(wptr);
    half8_t b1v = *(const half8_t*)(wptr + 1024);
    for (int i = 0; i < iters; ++i) {
        #pragma unroll
        for (int s = 0; s < 4; ++s)
            load_lds16(asrc + (size_t)s * 16 * SROW + (size_t)i * 64,
                       ldst + s * 2048);
        __syncthreads();
        half8_t n0, n1;
        if (i + 1 < iters) {
            n0 = *(const half8_t*)(wptr + 2048);
            n1 = *(const half8_t*)(wptr + 3072);
        }
        half8_t af;
        #pragma unroll
        for (int rt = 0; rt < 4; ++rt) {
            af = *(const half8_t*)&sA[(rt * 16 + lr) * 128 + ag0];
            acc[rt] = __builtin_amdgcn_mfma_f32_16x16x32_f16(af, b0, acc[rt], 0, 0, 0);
        }
        #pragma unroll
        for (int rt = 0; rt < 4; ++rt) {
            af = *(const half8_t*)&sA[(rt * 16 + lr) * 128 + ag1];
            acc[rt] = __builtin_amdgcn_mfma_f32_16x16x32_f16(af, b1v, acc[rt], 0, 0, 0);
        }
        __syncthreads();
        wptr += 2048;
        b0 = n0; b1v = n1;
    }

    float* scr = (float*)sA;
    if (kh == 1) {
        #pragma unroll
        for (int rt = 0; rt < 4; ++rt) {
            int slot = (hw * 4 + rt) * 64 + lane;
            *(float4_t*)&scr[slot * 4] = acc[rt];
        }
    }
    __syncthreads();
    if (kh != 0) return;
    #pragma unroll
    for (int rt = 0; rt < 4; ++rt) {
        int slot = (hw * 4 + rt) * 64 + lane;
        acc[rt] += *(const float4_t*)&scr[slot * 4];
    }

    const int j = h0 + hw * 16 + lr;
    const float bj = blin[j];
    #pragma unroll
    for (int rt = 0; rt < 4; ++rt) {
        #pragma unroll
        for (int e = 0; e < 4; ++e) {
            const int brow = m0 + rt * 16 + lq * 4 + e;
            float s = acc[rt][e] + bj;
            outp[(size_t)brow * (NST_ * I_) + j] = s;
            if (xdst) xdst[(size_t)brow * SROW + j] = (_Float16)s;
        }
    }
}

// ---------------- fused multi-role dispatch --------------------------------
struct StepArgs {
    int nL2, nL1, nProj, nCopy;
    const _Float16 *l2Alo, *l2Ahi; _Float16* l2H; float* c2;
    const _Float16 *l1Alo, *l1Ahi; _Float16* l1H; float* c1;
    const _Float16* pA; float* pOut; _Float16* pXdst;
    const float* xsrc; _Float16* xdst;
    const _Float16 *W1p, *W2p, *Wlp;
    const float *b1, *b2, *blin;
};

__global__ __launch_bounds__(256, 2) void fused_step(StepArgs a) {
    __shared__ __align__(16) _Float16 sA[32768];   // 64 KB (2 x 32 KB bufs)
    int bid = blockIdx.x;
    if (bid < a.nL2) {
        gemm_body(sA, a.l2Alo, a.l2Ahi, a.W2p, 16, 32, a.b2, a.c2, a.l2H, bid);
    } else if ((bid -= a.nL2) < a.nL1) {
        gemm_body(sA, a.l1Alo, a.l1Ahi, a.W1p, 9, 18, a.b1, a.c1, a.l1H, bid);
    } else if ((bid -= a.nL1) < a.nProj) {
        proj_body(sA, a.pA, a.Wlp, a.blin, a.pOut, a.pXdst, bid);
    } else {
        bid -= a.nProj;
        int base = bid * 256 + threadIdx.x;
        for (int k = base; k < B_ * I_; k += a.nCopy * 256) {
            int b = k >> 6, i = k & 63;
            a.xdst[(size_t)b * SROW + i] = (_Float16)a.xsrc[(size_t)b * (T_ * I_) + i];
        }
    }
}

// ---------------------------------------------------------------------------
extern "C" void kernel_launch(void* const* d_in, const int* in_sizes, int n_in,
                              void* d_out, int out_size, void* d_ws, size_t ws_size,
                              hipStream_t stream) {
    (void)in_sizes; (void)n_in; (void)out_size; (void)ws_size;
    const float* x    = (const float*)d_in[0];
    const float* Wih1 = (const float*)d_in[1];
    const float* Whh1 = (const float*)d_in[2];
    const float* bih1 = (const float*)d_in[3];
    const float* bhh1 = (const float*)d_in[4];
    const float* Wih2 = (const float*)d_in[5];
    const float* Whh2 = (const float*)d_in[6];
    const float* bih2 = (const float*)d_in[7];
    const float* bhh2 = (const float*)d_in[8];
    const float* Wlin = (const float*)d_in[9];
    const float* blin = (const float*)d_in[10];
    float* out = (float*)d_out;

    char* p = (char*)d_ws;
    auto alloc = [&](size_t bytes) {
        char* r = p; p += (bytes + 255) & ~(size_t)255; return r;
    };
    _Float16* W1p = (_Float16*)alloc((size_t)4096 * 1152 * 2);
    _Float16* W2p = (_Float16*)alloc((size_t)4096 * 2048 * 2);
    _Float16* Wlp = (_Float16*)alloc((size_t)64 * 1024 * 2);
    _Float16* S[3];
    for (int i = 0; i < 3; ++i) S[i] = (_Float16*)alloc((size_t)B_ * SROW * 2);
    float* c1 = (float*)alloc((size_t)B_ * H_ * 4);
    float* c2 = (float*)alloc((size_t)B_ * H_ * 4);
    float* b1 = (float*)alloc(4096 * 4);
    float* b2 = (float*)alloc(4096 * 4);

    for (int i = 0; i < 3; ++i)
        hipMemsetAsync(S[i], 0, (size_t)B_ * SROW * 2, stream);
    hipMemsetAsync(c1, 0, (size_t)B_ * H_ * 4, stream);
    hipMemsetAsync(c2, 0, (size_t)B_ * H_ * 4, stream);

    {
        const size_t total = 589824 + 1048576 + 8192 + 65536 + 65536 + 8192;
        convert_all<<<(int)((total + 255) / 256), 256, 0, stream>>>(
            x, Wih1, Whh1, bih1, bhh1, Wih2, Whh2, bih2, bhh2, Wlin,
            W1p, W2p, Wlp, S[0] + 1024, S[1] + 1024, b1, b2);
    }

    StepArgs a{};
    a.W1p = W1p; a.W2p = W2p; a.Wlp = Wlp;
    a.b1 = b1; a.b2 = b2; a.blin = blin;
    a.c1 = c1; a.c2 = c2;

    // prologue: L1(0) alone
    {
        StepArgs q = a;
        q.nL2 = 0; q.nL1 = 256; q.nProj = 0; q.nCopy = 0;
        q.l1Alo = S[0]; q.l1Ahi = S[0] + 576; q.l1H = S[1];
        fused_step<<<256, 256, 0, stream>>>(q);
    }

    // main phase: D_t = {L2(t), L1(t+1), proj(t-1), xcopy(t+2)}
    for (int t = 0; t <= 62; ++t) {
        _Float16* Sp = S[t % 3];
        _Float16* Sq = S[(t + 1) % 3];
        _Float16* Sn = S[(t + 2) % 3];
        StepArgs q = a;
        q.nL2 = 256; q.nL1 = 256;
        q.nProj = (t >= 1) ? 32 : 0;
        q.nCopy = (t <= 61) ? 16 : 0;
        q.l2Alo = Sq; q.l2Ahi = Sp + 1152; q.l2H = Sq + 1152;
        q.l1Alo = Sq; q.l1Ahi = Sq + 576; q.l1H = Sn;
        q.pA = Sp + 1152; q.pOut = out + (size_t)(t - 1) * I_; q.pXdst = nullptr;
        q.xsrc = x + (size_t)(t + 2) * I_; q.xdst = Sn + 1024;
        int grid = q.nL2 + q.nL1 + q.nProj + q.nCopy;
        fused_step<<<grid, 256, 0, stream>>>(q);
    }

    // t=63: {L2(63), proj(62)}, then {proj(63) + x(64) feedback}
    {
        StepArgs q = a;
        q.nL2 = 256; q.nL1 = 0; q.nProj = 32; q.nCopy = 0;
        q.l2Alo = S[1]; q.l2Ahi = S[0] + 1152; q.l2H = S[1] + 1152;
        q.pA = S[0] + 1152; q.pOut = out + (size_t)62 * I_; q.pXdst = nullptr;
        fused_step<<<288, 256, 0, stream>>>(q);
    }
    {
        StepArgs q = a;
        q.nL2 = 0; q.nL1 = 0; q.nProj = 32; q.nCopy = 0;
        q.pA = S[1] + 1152; q.pOut = out + (size_t)63 * I_; q.pXdst = S[1] + 1024;
        fused_step<<<32, 256, 0, stream>>>(q);
    }

    // future phase: serial L1(t) -> L2(t) -> proj(t)
    for (int t = T_; t < NST_; ++t) {
        _Float16* Sp = S[t % 3];
        _Float16* Sq = S[(t + 1) % 3];
        {
            StepArgs q = a;
            q.nL2 = 0; q.nL1 = 256; q.nProj = 0; q.nCopy = 0;
            q.l1Alo = Sp; q.l1Ahi = Sp + 576; q.l1H = Sq;
            fused_step<<<256, 256, 0, stream>>>(q);
        }
        {
            StepArgs q = a;
            q.nL2 = 256; q.nL1 = 0; q.nProj = 0; q.nCopy = 0;
            q.l2Alo = Sq; q.l2Ahi = Sp + 1152; q.l2H = Sq + 1152;
            fused_step<<<256, 256, 0, stream>>>(q);
        }
        {
            StepArgs q = a;
            q.nL2 = 0; q.nL1 = 0; q.nProj = 32; q.nCopy = 0;
            q.pA = Sq + 1152; q.pOut = out + (size_t)t * I_;
            q.pXdst = (t + 1 < NST_) ? (Sq + 1024) : nullptr;
            fused_step<<<32, 256, 0, stream>>>(q);
        }
    }
}